// Round 6
// baseline (1027.826 us; speedup 1.0000x reference)
//
#include <hip/hip_runtime.h>

typedef __bf16 bf16;
typedef __bf16 bf16x8 __attribute__((ext_vector_type(8)));
typedef __bf16 bf16x4 __attribute__((ext_vector_type(4)));
typedef float  f32x4  __attribute__((ext_vector_type(4)));

#define SEQ     2048
#define HIDDEN  3584
#define NHEADS  28
#define NKV     4
#define HD      128
#define SCALING 0.08838834764831845f
#define L2E     1.44269504088896341f
#define QSCALE  (SCALING * L2E)

typedef __attribute__((address_space(1))) void gvoid;
typedef __attribute__((address_space(3))) void lvoid;

__device__ __forceinline__ void gl_lds16(const void* g, void* l) {
  __builtin_amdgcn_global_load_lds((gvoid*)g, (lvoid*)l, 16, 0, 0);
}

// ---------------- fp32 -> bf16 convert ----------------
__global__ void f2bf_kernel(const float* __restrict__ in, bf16* __restrict__ out, int n8) {
  int i = blockIdx.x * 256 + threadIdx.x;
  if (i >= n8) return;
  const f32x4* p = (const f32x4*)(in + (size_t)i * 8);
  f32x4 x = p[0], y = p[1];
  bf16x8 o;
  o[0] = (bf16)x[0]; o[1] = (bf16)x[1]; o[2] = (bf16)x[2]; o[3] = (bf16)x[3];
  o[4] = (bf16)y[0]; o[5] = (bf16)y[1]; o[6] = (bf16)y[2]; o[7] = (bf16)y[3];
  *(bf16x8*)(out + (size_t)i * 8) = o;
}

// ---------------- NT GEMM: C[m][n] = sum_k A[m][k] * W[n][k] (+bias) ----------------
template <int MODE>
__global__ __launch_bounds__(256, 2) void gemm_kernel(
    const bf16* __restrict__ A,
    const bf16* __restrict__ W0, const bf16* __restrict__ W1, const bf16* __restrict__ W2,
    const float* __restrict__ b0, const float* __restrict__ b1, const float* __restrict__ b2,
    float* __restrict__ outF,
    bf16* __restrict__ Qb, bf16* __restrict__ Kb, bf16* __restrict__ Vb) {
  __shared__ bf16 As[128 * 32];
  __shared__ bf16 Bs[128 * 32];
  const int tid = threadIdx.x;
  const int w = tid >> 6, lane = tid & 63;
  const int wm = (w >> 1) * 64, wn = (w & 1) * 64;
  const int m0 = blockIdx.y * 128;
  const int n0 = blockIdx.x * 128;
  const int K = HIDDEN;

  const bf16* Bsrc;
  int nbase;
  if (MODE == 0) { Bsrc = W0; nbase = 0; }
  else {
    if (n0 < 3584)      { Bsrc = W0; nbase = 0; }
    else if (n0 < 4096) { Bsrc = W1; nbase = 3584; }
    else                { Bsrc = W2; nbase = 4096; }
  }
  const int bn0 = n0 - nbase;

  f32x4 acc[4][4];
#pragma unroll
  for (int i = 0; i < 4; i++)
#pragma unroll
    for (int j = 0; j < 4; j++) { f32x4 z = {0.f, 0.f, 0.f, 0.f}; acc[i][j] = z; }

  const int srow = lane >> 2;
  const int scol = (lane & 3) * 8;
  const int mr = lane & 15, kq = (lane >> 4) * 8;

  for (int k0 = 0; k0 < K; k0 += 32) {
    __syncthreads();
#pragma unroll
    for (int c = 0; c < 2; c++) {
      int chunk = w * 2 + c;
      int row = chunk * 16 + srow;
      gl_lds16(&A[(size_t)(m0 + row) * K + k0 + scol], &As[chunk * 512]);
      gl_lds16(&Bsrc[(size_t)(bn0 + row) * K + k0 + scol], &Bs[chunk * 512]);
    }
    __syncthreads();
    bf16x8 a[4], b[4];
#pragma unroll
    for (int i = 0; i < 4; i++) a[i] = *(const bf16x8*)&As[(wm + i * 16 + mr) * 32 + kq];
#pragma unroll
    for (int j = 0; j < 4; j++) b[j] = *(const bf16x8*)&Bs[(wn + j * 16 + mr) * 32 + kq];
#pragma unroll
    for (int i = 0; i < 4; i++)
#pragma unroll
      for (int j = 0; j < 4; j++)
        acc[i][j] = __builtin_amdgcn_mfma_f32_16x16x32_bf16(a[i], b[j], acc[i][j], 0, 0, 0);
  }

  const int quad = lane >> 4, col = lane & 15;
  if (MODE == 0) {
#pragma unroll
    for (int i = 0; i < 4; i++)
#pragma unroll
      for (int j = 0; j < 4; j++) {
        int n = n0 + wn + j * 16 + col;
#pragma unroll
        for (int r = 0; r < 4; r++) {
          int m = m0 + wm + i * 16 + quad * 4 + r;
          outF[(size_t)m * 3584 + n] = acc[i][j][r];
        }
      }
  } else {
    bf16* dst; int H; const float* bias; float mult;
    if (n0 < 3584)      { dst = Qb; H = NHEADS; bias = b0; mult = QSCALE; }
    else if (n0 < 4096) { dst = Kb; H = NKV;    bias = b1; mult = 1.0f; }
    else                { dst = Vb; H = NKV;    bias = b2; mult = 1.0f; }
#pragma unroll
    for (int j = 0; j < 4; j++) {
      int nl = bn0 + wn + j * 16 + col;
      float bb = bias[nl];
      int hh = nl >> 7, d = nl & 127;
#pragma unroll
      for (int i = 0; i < 4; i++)
#pragma unroll
        for (int r = 0; r < 4; r++) {
          int m = m0 + wm + i * 16 + quad * 4 + r;
          int bidx = m >> 11, s = m & 2047;
          dst[(((size_t)bidx * H + hh) * SEQ + s) * HD + d] = (bf16)((acc[i][j][r] + bb) * mult);
        }
    }
  }
}

// ---------------- RoPE (in place, bf16) ----------------
__global__ void rope_kernel(bf16* __restrict__ X, const float* __restrict__ cosp,
                            const float* __restrict__ sinp, int nheads) {
  int idx = blockIdx.x * 256 + threadIdx.x;
  int dg = idx & 15;
  int s = (idx >> 4) & 2047;
  int bh = idx >> 15;
  int b = bh / nheads;
  int d = dg * 4;
  f32x4 c = *(const f32x4*)&cosp[((size_t)b * SEQ + s) * HD + d];
  f32x4 sn = *(const f32x4*)&sinp[((size_t)b * SEQ + s) * HD + d];
  bf16* p = X + ((size_t)bh * SEQ + s) * HD + d;
  bf16x4 lo = *(bf16x4*)p;
  bf16x4 hi = *(bf16x4*)(p + 64);
  bf16x4 nlo, nhi;
#pragma unroll
  for (int i = 0; i < 4; i++) {
    float l = (float)lo[i], h = (float)hi[i];
    nlo[i] = (bf16)(l * c[i] - h * sn[i]);
    nhi[i] = (bf16)(h * c[i] + l * sn[i]);
  }
  *(bf16x4*)p = nlo;
  *(bf16x4*)(p + 64) = nhi;
}

// ---------------- V transpose per head: [S][D] -> [D][S] ----------------
__global__ void transpose_kernel(const bf16* __restrict__ V, bf16* __restrict__ Vt) {
  __shared__ bf16 t[32][33];
  int head = blockIdx.z;
  int s0 = blockIdx.x * 32, d0 = blockIdx.y * 32;
  const bf16* src = V + (size_t)head * SEQ * HD;
  bf16* dst = Vt + (size_t)head * HD * SEQ;
#pragma unroll
  for (int i = 0; i < 4; i++)
    t[threadIdx.y + i * 8][threadIdx.x] =
        src[(size_t)(s0 + threadIdx.y + i * 8) * HD + d0 + threadIdx.x];
  __syncthreads();
#pragma unroll
  for (int i = 0; i < 4; i++)
    dst[(size_t)(d0 + threadIdx.y + i * 8) * SEQ + s0 + threadIdx.x] =
        t[threadIdx.x][threadIdx.y + i * 8];
}

__device__ __forceinline__ float vmax4(f32x4 a) {
  return fmaxf(fmaxf(a[0], a[1]), fmaxf(a[2], a[3]));
}

// ---------------- Flash attention (barrier-free, K/V direct from global) -------
// grid (S/128, 28, 2), x reversed; block 256 = 4 INDEPENDENT waves (no
// __syncthreads anywhere). Wave w owns 32 q rows [q0+32w, q0+32w+32) as two
// 16-row MFMA subtiles; lane's q = col (+16), keys in-lane.
// K/V A-fragments load straight from global (16x64B segments/instr, L1/L2
// served, LLC-resident) — every ak/av feeds both subtiles' MFMAs. Only the
// P quad-transpose round-trips LDS (per-wave region, lgkmcnt only).
// launch_bounds(256,2): VGPR cap 256 — round 4 showed tighter caps spill.
__global__ __launch_bounds__(256, 2) void flash_kernel(
    const bf16* __restrict__ Q, const bf16* __restrict__ K,
    const bf16* __restrict__ Vt, bf16* __restrict__ attn) {
  __shared__ bf16 Ps[4][2][16 * 64];   // [wave][subtile][q][key] swizzled, 16 KB

  const int tid = threadIdx.x, w = tid >> 6, lane = tid & 63;
  const int quad = lane >> 4, col = lane & 15;
  const int qt = (int)gridDim.x - 1 - (int)blockIdx.x;
  const int q0 = qt * 128;
  const int h = blockIdx.y, b = blockIdx.z;
  const int kvh = h / (NHEADS / NKV);
  const int qb = q0 + w * 32;
  const bf16* Qg = Q + (((size_t)b * NHEADS + h) * SEQ + qb) * HD;
  const bf16* Kg = K + ((size_t)b * NKV + kvh) * SEQ * HD;
  const bf16* Vg = Vt + ((size_t)b * NKV + kvh) * HD * SEQ;

  // Q fragments (B-operand), both subtiles: n = col(+16), k = kc*32 + quad*8 + 0..7
  bf16x8 aq0[4], aq1[4];
#pragma unroll
  for (int kc = 0; kc < 4; kc++) {
    aq0[kc] = *(const bf16x8*)&Qg[(size_t)col * HD + kc * 32 + quad * 8];
    aq1[kc] = *(const bf16x8*)&Qg[(size_t)(col + 16) * HD + kc * 32 + quad * 8];
  }

  f32x4 o0[8], o1[8];
#pragma unroll
  for (int nt = 0; nt < 8; nt++) { f32x4 z = {0.f, 0.f, 0.f, 0.f}; o0[nt] = z; o1[nt] = z; }
  float mi0 = -1e30f, li0 = 0.f, mi1 = -1e30f, li1 = 0.f;
  const int myq0 = qb + col, myq1 = qb + 16 + col;
  const int nkt = (qb + 31) / 64 + 1;

  for (int kt = 0; kt < nkt; kt++) {
    const int kt0 = kt * 64;
    // S^T = K Q^T for both subtiles; ak direct from global, feeds 2 MFMAs
    f32x4 s0[4], s1[4];
#pragma unroll
    for (int j = 0; j < 4; j++) { f32x4 z = {0.f, 0.f, 0.f, 0.f}; s0[j] = z; s1[j] = z; }
#pragma unroll
    for (int kc = 0; kc < 4; kc++)
#pragma unroll
      for (int j = 0; j < 4; j++) {
        bf16x8 ak = *(const bf16x8*)&Kg[(size_t)(kt0 + j * 16 + col) * HD + kc * 32 + quad * 8];
        s0[j] = __builtin_amdgcn_mfma_f32_16x16x32_bf16(ak, aq0[kc], s0[j], 0, 0, 0);
        s1[j] = __builtin_amdgcn_mfma_f32_16x16x32_bf16(ak, aq1[kc], s1[j], 0, 0, 0);
      }
    // causal mask (only on diagonal-region tiles)
    const int kb = kt0 + quad * 4;
    if (kt0 + 63 > qb) {
#pragma unroll
      for (int j = 0; j < 4; j++)
#pragma unroll
        for (int r = 0; r < 4; r++)
          if (kb + j * 16 + r > myq0) s0[j][r] = -1e30f;
    }
    if (kt0 + 63 > qb + 16) {
#pragma unroll
      for (int j = 0; j < 4; j++)
#pragma unroll
        for (int r = 0; r < 4; r++)
          if (kb + j * 16 + r > myq1) s1[j][r] = -1e30f;
    }
    // online softmax, two independent chains (ILP)
    f32x4 a01, a23, b01, b23;
#pragma unroll
    for (int r = 0; r < 4; r++) {
      a01[r] = fmaxf(s0[0][r], s0[1][r]); a23[r] = fmaxf(s0[2][r], s0[3][r]);
      b01[r] = fmaxf(s1[0][r], s1[1][r]); b23[r] = fmaxf(s1[2][r], s1[3][r]);
    }
    float tm0 = fmaxf(vmax4(a01), vmax4(a23));
    float tm1 = fmaxf(vmax4(b01), vmax4(b23));
    tm0 = fmaxf(tm0, __shfl_xor(tm0, 16, 64));
    tm1 = fmaxf(tm1, __shfl_xor(tm1, 16, 64));
    tm0 = fmaxf(tm0, __shfl_xor(tm0, 32, 64));
    tm1 = fmaxf(tm1, __shfl_xor(tm1, 32, 64));
    float mn0 = fmaxf(mi0, tm0), mn1 = fmaxf(mi1, tm1);
    float al0 = exp2f(mi0 - mn0), al1 = exp2f(mi1 - mn1);
    mi0 = mn0; mi1 = mn1;
    float rs0 = 0.f, rs1 = 0.f;
#pragma unroll
    for (int j = 0; j < 4; j++) {
      f32x4 p0, p1;
#pragma unroll
      for (int r = 0; r < 4; r++) { p0[r] = exp2f(s0[j][r] - mn0); p1[r] = exp2f(s1[j][r] - mn1); }
      rs0 += (p0[0] + p0[1]) + (p0[2] + p0[3]);
      rs1 += (p1[0] + p1[1]) + (p1[2] + p1[3]);
      bf16x4 q0b, q1b;
#pragma unroll
      for (int r = 0; r < 4; r++) { q0b[r] = (bf16)p0[r]; q1b[r] = (bf16)p1[r]; }
      const int off = col * 64 + (((j * 2 + (quad >> 1)) ^ (col & 7)) << 3) + (quad & 1) * 4;
      *(bf16x4*)&Ps[w][0][off] = q0b;
      *(bf16x4*)&Ps[w][1][off] = q1b;
    }
    li0 = li0 * al0 + rs0;
    li1 = li1 * al1 + rs1;
#pragma unroll
    for (int nt = 0; nt < 8; nt++)
#pragma unroll
      for (int r = 0; r < 4; r++) { o0[nt][r] *= al0; o1[nt][r] *= al1; }
    // O^T += V^T P^T ; av direct from global, feeds both subtiles
#pragma unroll
    for (int ks = 0; ks < 2; ks++) {
      const int poff = col * 64 + (((ks * 4 + quad) ^ (col & 7)) << 3);
      bf16x8 bp0 = *(const bf16x8*)&Ps[w][0][poff];
      bf16x8 bp1 = *(const bf16x8*)&Ps[w][1][poff];
#pragma unroll
      for (int nt = 0; nt < 8; nt++) {
        bf16x8 av = *(const bf16x8*)&Vg[(size_t)(nt * 16 + col) * SEQ + kt0 + ks * 32 + quad * 8];
        o0[nt] = __builtin_amdgcn_mfma_f32_16x16x32_bf16(av, bp0, o0[nt], 0, 0, 0);
        o1[nt] = __builtin_amdgcn_mfma_f32_16x16x32_bf16(av, bp1, o1[nt], 0, 0, 0);
      }
    }
  }

  // epilogue: complete l across quads, store O^T (lane q=col, d = nt*16+quad*4+r)
  li0 += __shfl_xor(li0, 16, 64); li0 += __shfl_xor(li0, 32, 64);
  li1 += __shfl_xor(li1, 16, 64); li1 += __shfl_xor(li1, 32, 64);
  float r0 = 1.0f / li0, r1 = 1.0f / li1;
  bf16* d0 = attn + ((size_t)b * SEQ + qb + col) * HIDDEN + h * HD + quad * 4;
  bf16* d1 = attn + ((size_t)b * SEQ + qb + 16 + col) * HIDDEN + h * HD + quad * 4;
#pragma unroll
  for (int nt = 0; nt < 8; nt++) {
    bf16x4 ob0, ob1;
#pragma unroll
    for (int r = 0; r < 4; r++) { ob0[r] = (bf16)(o0[nt][r] * r0); ob1[r] = (bf16)(o1[nt][r] * r1); }
    *(bf16x4*)&d0[nt * 16] = ob0;
    *(bf16x4*)&d1[nt * 16] = ob1;
  }
}

extern "C" void kernel_launch(void* const* d_in, const int* in_sizes, int n_in,
                              void* d_out, int out_size, void* d_ws, size_t ws_size,
                              hipStream_t stream) {
  const float* hidden = (const float*)d_in[0];
  const float* cosp   = (const float*)d_in[1];
  const float* sinp   = (const float*)d_in[2];
  const float* Wq = (const float*)d_in[4];
  const float* bq = (const float*)d_in[5];
  const float* Wk = (const float*)d_in[6];
  const float* bk = (const float*)d_in[7];
  const float* Wv = (const float*)d_in[8];
  const float* bv = (const float*)d_in[9];
  const float* Wo = (const float*)d_in[10];
  float* out = (float*)d_out;

  char* ws = (char*)d_ws;
  size_t off = 0;
  auto alloc = [&](size_t bytes) {
    char* p = ws + off;
    off += (bytes + 255) & ~(size_t)255;
    return p;
  };
  const size_t M = 4096;
  bf16* hb  = (bf16*)alloc(M * HIDDEN * 2);
  bf16* wqb = (bf16*)alloc((size_t)3584 * 3584 * 2);
  bf16* wkb = (bf16*)alloc((size_t)512 * 3584 * 2);
  bf16* wvb = (bf16*)alloc((size_t)512 * 3584 * 2);
  bf16* wob = (bf16*)alloc((size_t)3584 * 3584 * 2);
  bf16* Qb  = (bf16*)alloc((size_t)2 * NHEADS * SEQ * HD * 2);
  bf16* Kb  = (bf16*)alloc((size_t)2 * NKV * SEQ * HD * 2);
  bf16* Vb  = (bf16*)alloc((size_t)2 * NKV * SEQ * HD * 2);
  bf16* Vt  = (bf16*)alloc((size_t)2 * NKV * SEQ * HD * 2);
  bf16* attn = hb;  // hidden dead after QKV GEMM

  f2bf_kernel<<<(4096 * 3584 / 8 + 255) / 256, 256, 0, stream>>>(hidden, hb, 4096 * 3584 / 8);
  f2bf_kernel<<<(3584 * 3584 / 8 + 255) / 256, 256, 0, stream>>>(Wq, wqb, 3584 * 3584 / 8);
  f2bf_kernel<<<(512 * 3584 / 8 + 255) / 256, 256, 0, stream>>>(Wk, wkb, 512 * 3584 / 8);
  f2bf_kernel<<<(512 * 3584 / 8 + 255) / 256, 256, 0, stream>>>(Wv, wvb, 512 * 3584 / 8);
  f2bf_kernel<<<(3584 * 3584 / 8 + 255) / 256, 256, 0, stream>>>(Wo, wob, 3584 * 3584 / 8);

  gemm_kernel<1><<<dim3(36, 32), 256, 0, stream>>>(hb, wqb, wkb, wvb, bq, bk, bv,
                                                   nullptr, Qb, Kb, Vb);
  rope_kernel<<<2 * NHEADS * SEQ * 16 / 256, 256, 0, stream>>>(Qb, cosp, sinp, NHEADS);
  rope_kernel<<<2 * NKV * SEQ * 16 / 256, 256, 0, stream>>>(Kb, cosp, sinp, NKV);
  transpose_kernel<<<dim3(64, 4, 8), dim3(32, 8), 0, stream>>>(Vb, Vt);
  flash_kernel<<<dim3(16, 28, 2), 256, 0, stream>>>(Qb, Kb, Vt, attn);
  gemm_kernel<0><<<dim3(28, 32), 256, 0, stream>>>(attn, wob, nullptr, nullptr,
                                                   nullptr, nullptr, nullptr,
                                                   out, nullptr, nullptr, nullptr);
}